// Round 6
// baseline (275.996 us; speedup 1.0000x reference)
//
#include <hip/hip_runtime.h>
#include <hip/hip_bf16.h>
#include <stdint.h>

typedef unsigned short u16;
typedef unsigned int   u32;

#define N_DIM  1024
#define IN_DIM 1024
#define H_DIM  64
#define BATCH  16

typedef __bf16 bf16x8 __attribute__((ext_vector_type(8)));
typedef float  f32x4  __attribute__((ext_vector_type(4)));

// round-to-nearest-even fp32 -> bf16 (bit pattern)
__device__ inline u16 f2bf(float f) {
    union { float f; u32 u; } v; v.f = f;
    u32 u = v.u;
    return (u16)((u + 0x7fffu + ((u >> 16) & 1u)) >> 16);
}
// packed pair: v_cvt_pk_bf16_f32 when available
__device__ inline u32 pack2(float a, float b) {
    __hip_bfloat162 h = __float22bfloat162_rn(float2{a, b});
    union { __hip_bfloat162 h; u32 u; } cv; cv.h = h; return cv.u;
}

// async global->LDS, 16B per lane. LDS dest must be wave-uniform base + lane*16.
__device__ inline void gl_lds16(const u16* g, u16* l) {
    __builtin_amdgcn_global_load_lds(
        (const __attribute__((address_space(1))) u32*)g,
        (__attribute__((address_space(3))) u32*)l, 16, 0, 0);
}

// ---------------------------------------------------------------------------
// prep (merged): blocks 0..255 = G transpose tiles + per-jtile rowsum partials
//                blocks 256..767 = Q/Kw transpose-cast
__global__ __launch_bounds__(256) void prep(
        const float* __restrict__ G, const float* __restrict__ Q,
        const float* __restrict__ Kw, u16* __restrict__ Gbt,
        float* __restrict__ Grp, u16* __restrict__ QT, u16* __restrict__ KwT) {
    int bid = blockIdx.x;
    if (bid >= 256) {
        int idx = (bid - 256) * 256 + threadIdx.x;      // 0 .. 131071
        const float* src = (idx < 65536) ? Q : Kw;
        u16* dst = (idx < 65536) ? QT : KwT;
        int i = idx & 65535;
        int h = i >> 10;         // 0..63
        int n = i & 1023;        // 0..1023 (contiguous store)
        dst[h * 1024 + n] = f2bf(src[n * 64 + h]);
        return;
    }
    __shared__ float tile[64][65];
    int jt = bid & 15, it = bid >> 4;
    int i0 = it * 64, j0 = jt * 64;
    int tx = threadIdx.x & 63, ty = threadIdx.x >> 6;   // ty 0..3
    for (int r = 0; r < 16; ++r) {
        int i = ty * 16 + r;
        tile[i][tx] = G[(size_t)(i0 + i) * 1024 + j0 + tx];
    }
    __syncthreads();
    for (int r = 0; r < 16; ++r) {
        int j = ty * 16 + r;
        Gbt[(size_t)(j0 + j) * 1024 + i0 + tx] = f2bf(tile[tx][j]);
    }
    if (ty == 0) {
        float sum = 0.f;
        for (int j = 0; j < 64; ++j) sum += tile[tx][j];
        Grp[jt * 1024 + i0 + tx] = sum;                 // plain store, no atomics
    }
}

// ---------------------------------------------------------------------------
// qkt (merged): z==0 -> q[b][n][h] = sum_i s[n][b][i] Qw[i][h]
//               z==1 -> kt[b][i][h] = sum_n s[n][b][i] Kw[n][h]
__global__ __launch_bounds__(512, 4) void qkt(
        const float* __restrict__ s, const u16* __restrict__ QT,
        const u16* __restrict__ KwT, const float* __restrict__ Grp,
        u16* __restrict__ qws, u16* __restrict__ ktws, float* __restrict__ Grsum) {
    int b = blockIdx.y;
    int t = threadIdx.x, lane = t & 63, w = t >> 6, quad = lane >> 4, l15 = lane & 15;
    __shared__ __align__(16) u16 sh[2][2][64][34];     // kt staging; q aliases as 16KB reduce
    float* red = (float*)sh;

    if (blockIdx.z == 0) {
        // ---------------- q role ----------------
        if (blockIdx.y == 0 && t < 64) {               // Grsum finalize (16 x-blocks cover 1024 i)
            int i = blockIdx.x * 64 + t;
            float g = 0.f;
            for (int jt = 0; jt < 16; ++jt) g += Grp[jt * 1024 + i];
            Grsum[i] = g;
        }
        int n0 = blockIdx.x * 64;
        int wm = (w & 3) * 16;                         // m-quarter within 64
        int kb = (w >> 2) * 512;                       // k-half
        const float* arow = s + (size_t)(n0 + wm + l15) * (BATCH * IN_DIM)
                              + (size_t)b * IN_DIM + kb + quad * 8;
        const u16* bbase = QT + (size_t)l15 * 1024 + kb + quad * 8;

        f32x4 acc[4] = {};
        float4 A0[3], A1[3];
        bf16x8 Bf[2][4];
        A0[0] = ((const float4*)arow)[0];
        A1[0] = ((const float4*)arow)[1];
        A0[1] = ((const float4*)(arow + 32))[0];
        A1[1] = ((const float4*)(arow + 32))[1];
#pragma unroll
        for (int ct = 0; ct < 4; ++ct)
            Bf[0][ct] = *(const bf16x8*)&bbase[ct * 16384];

#pragma unroll
        for (int st = 0; st < 16; ++st) {              // 16 steps of k=32
            int cur = st % 3, cb = st & 1;
            if (st < 14) {                             // A prefetch depth 3 (HBM)
                const float4* ap = (const float4*)(arow + (size_t)(st + 2) * 32);
                A0[(st + 2) % 3] = ap[0];
                A1[(st + 2) % 3] = ap[1];
            }
            if (st < 15) {                             // B prefetch depth 2 (L2)
#pragma unroll
                for (int ct = 0; ct < 4; ++ct)
                    Bf[cb ^ 1][ct] = *(const bf16x8*)&bbase[ct * 16384 + (st + 1) * 32];
            }
            float4 fa = A0[cur], fb = A1[cur];
            union { uint4 u; bf16x8 v; } cu;
            cu.u = (uint4){ pack2(fa.x, fa.y), pack2(fa.z, fa.w),
                            pack2(fb.x, fb.y), pack2(fb.z, fb.w) };
#pragma unroll
            for (int ct = 0; ct < 4; ++ct)
                acc[ct] = __builtin_amdgcn_mfma_f32_16x16x32_bf16(cu.v, Bf[cb][ct], acc[ct], 0, 0, 0);
        }

        // cross-k-half reduce through LDS
        if (w >= 4) {
            float* dst = red + ((w - 4) * 64 + lane) * 16;
#pragma unroll
            for (int ct = 0; ct < 4; ++ct) *(f32x4*)&dst[ct * 4] = acc[ct];
        }
        __syncthreads();
        if (w < 4) {
            const float* sp2 = red + (w * 64 + lane) * 16;
            u16* ob = qws + (size_t)b * 65536;
#pragma unroll
            for (int ct = 0; ct < 4; ++ct) {
                f32x4 o = *(const f32x4*)&sp2[ct * 4];
#pragma unroll
                for (int r = 0; r < 4; ++r) {
                    int m = n0 + wm + quad * 4 + r;
                    ob[(size_t)m * 64 + ct * 16 + l15] = f2bf(acc[ct][r] + o[r]);
                }
            }
        }
        return;
    }

    // ---------------- kt role ----------------
    int i0 = blockIdx.x * 64;
    int half = w >> 2;                                 // compute n-half
    int wm = (w & 3) * 16;                             // i-quarter
    int shalf = t >> 8, nr = (t & 255) >> 3, iofs = (t & 7) * 8;  // staging role
    const float* sp = s + (size_t)(shalf * 512 + nr) * (BATCH * IN_DIM)
                        + (size_t)b * IN_DIM + i0 + iofs;
    const u16* bbase = KwT + (size_t)l15 * 1024 + half * 512 + quad * 8;

    f32x4 acc[4] = {};
    float4 P0[2], P1[2];
    bf16x8 Bf[2][4];
    P0[0] = ((const float4*)sp)[0];
    P1[0] = ((const float4*)sp)[1];
    {
        const float4* p = (const float4*)(sp + (size_t)32 * 16384);
        P0[1] = p[0]; P1[1] = p[1];
    }
#pragma unroll
    for (int ct = 0; ct < 4; ++ct)
        Bf[0][ct] = *(const bf16x8*)&bbase[ct * 16384];

#pragma unroll
    for (int c = 0; c < 16; ++c) {                     // 16 chunks of n=32 per half
        int buf = c & 1;
        float4 fa = P0[buf], fb = P1[buf];
        u16* wp = &sh[shalf][buf][iofs][nr];
        wp[0]   = f2bf(fa.x);
        wp[34]  = f2bf(fa.y);
        wp[68]  = f2bf(fa.z);
        wp[102] = f2bf(fa.w);
        wp[136] = f2bf(fb.x);
        wp[170] = f2bf(fb.y);
        wp[204] = f2bf(fb.z);
        wp[238] = f2bf(fb.w);
        __syncthreads();                               // buf ready (both halves)
        if (c < 14) {                                  // prefetch chunk c+2 (HBM/L3)
            const float4* p = (const float4*)(sp + (size_t)(c + 2) * 32 * 16384);
            P0[buf] = p[0]; P1[buf] = p[1];
        }
        if (c < 15) {                                  // prefetch next B-frags (L2)
#pragma unroll
            for (int ct = 0; ct < 4; ++ct)
                Bf[(c + 1) & 1][ct] = *(const bf16x8*)&bbase[ct * 16384 + (c + 1) * 32];
        }
        const u32* ap = (const u32*)&sh[half][buf][wm + l15][quad * 8];
        union { u32 u[4]; bf16x8 v; } au;
        au.u[0] = ap[0]; au.u[1] = ap[1]; au.u[2] = ap[2]; au.u[3] = ap[3];
#pragma unroll
        for (int ct = 0; ct < 4; ++ct)
            acc[ct] = __builtin_amdgcn_mfma_f32_16x16x32_bf16(au.v, Bf[buf][ct], acc[ct], 0, 0, 0);
    }

    __syncthreads();                                   // staging reads all done
    if (w >= 4) {
        float* dst = red + ((w - 4) * 64 + lane) * 16;
#pragma unroll
        for (int ct = 0; ct < 4; ++ct) *(f32x4*)&dst[ct * 4] = acc[ct];
    }
    __syncthreads();
    if (w < 4) {
        const float* sp2 = red + (w * 64 + lane) * 16;
        u16* ob = ktws + (size_t)b * 65536;
#pragma unroll
        for (int ct = 0; ct < 4; ++ct) {
            f32x4 o = *(const f32x4*)&sp2[ct * 4];
#pragma unroll
            for (int r = 0; r < 4; ++r) {
                int i = i0 + wm + quad * 4 + r;
                ob[(size_t)i * 64 + ct * 16 + l15] = f2bf(acc[ct][r] + o[r]);
            }
        }
    }
}

// ---------------------------------------------------------------------------
// gemm_fused v6 = r2's proven two-barrier loop, retiled 128m x 128n so the
// grid becomes 1024 blocks = 4 blocks/CU (was 512 = 2/CU; occupancy was the
// binding constraint: MfmaUtil/VALUBusy/Occupancy all ~17-27%, grid-capped).
// Score phase identical to r2 (4 waves cover 128m x 32i; ktc pitch 72,
// conflict-free). Agg per wave: 64m x 64n (acc[4][4]). Bs halves to
// [2][128x32]. LDS 35840 B -> 4 blocks/CU; VGPR well under the 128 cap.
// Score redundancy 8x (vs 4x) is the accepted cost: MFMA/VALU had headroom.
__global__ __launch_bounds__(256, 4) void gemm_fused(
        const u16* __restrict__ qws, const u16* __restrict__ ktws,
        const u16* __restrict__ Gbt, const float* __restrict__ Grsum,
        float* __restrict__ out) {
    int b = blockIdx.z;
    int n0 = blockIdx.x * 128, m0 = blockIdx.y * 128;
    const u16* qb = qws  + (size_t)b * 65536;
    const u16* kb = ktws + (size_t)b * 65536;
    __shared__ __align__(16) u16 As[128 * 40];       // score->agg buffer, padded
    __shared__ __align__(16) u16 Bs[2][128 * 32];    // Gbt staging (gl_lds, dbuf)
    __shared__ __align__(16) u16 ktc[32 * 72];       // kt chunk, padded, single buf
    __shared__ __align__(16) float Grs[1024];
    __shared__ float rs[128];
    int t = threadIdx.x, lane = t & 63, w = t >> 6, quad = lane >> 4, l15 = lane & 15;
    int ti = w & 1;                              // score i-subtile (16 of 32)
    int wm = (w >> 1) * 64;                      // m-half (shared by score & agg)
    int wn = (w & 1) * 64;                       // agg n-half of 128

    ((float4*)Grs)[t] = ((const float4*)Grsum)[t];
    if (t < 128) rs[t] = 0.f;

    // K-invariant q B-frags: B[k=h][col=m], 8 contiguous h per lane
    bf16x8 qf[4][2];
#pragma unroll
    for (int j = 0; j < 4; ++j)
#pragma unroll
        for (int kick = 0; kick < 2; ++kick)
            qf[j][kick] = *(const bf16x8*)&qb[(size_t)(m0 + wm + j*16 + l15) * 64 + kick*32 + quad*8];

    // iter-0 staging: Gbt rows n0..n0+127, 32 cols
    int br = t >> 2, bc = (t & 3) * 8;
#pragma unroll
    for (int g4 = 0; g4 < 2; ++g4)
        gl_lds16(Gbt + (size_t)(n0 + br + g4*64) * 1024 + bc, &Bs[0][(br + g4*64) * 32 + bc]);
    int ir = t >> 3, ch = (t & 7) * 8;
    uint4 kreg = *(const uint4*)&kb[(size_t)ir * 64 + ch];

    f32x4 acc[4][4] = {};
    float partial[4] = {0.f, 0.f, 0.f, 0.f};

    for (int kk = 0; kk < 32; ++kk) {
        int buf = kk & 1;
        *(uint4*)&ktc[ir * 72 + ch] = kreg;        // single buf: prev reads done pre-barrier2
        __syncthreads();                           // barrier1: Bs[buf] + ktc ready
        // ---- score: S^T[i][m] for i-subtile ti, m in wave's 64-half
        f32x4 sacc[4] = {};
#pragma unroll
        for (int kick = 0; kick < 2; ++kick) {
            bf16x8 ktf = *(const bf16x8*)&ktc[(ti*16 + l15) * 72 + kick*32 + quad*8];
#pragma unroll
            for (int j = 0; j < 4; ++j)
                sacc[j] = __builtin_amdgcn_mfma_f32_16x16x32_bf16(ktf, qf[j][kick], sacc[j], 0, 0, 0);
        }
        if (kk < 31)
            kreg = *(const uint4*)&kb[(size_t)((kk + 1) * 32 + ir) * 64 + ch];
        // ---- epilogue: square, rowsum partial, pack to As
        float4 g = *(const float4*)&Grs[kk * 32 + ti * 16 + quad * 4];
#pragma unroll
        for (int j = 0; j < 4; ++j) {
            float v0 = sacc[j][0] * 0.125f + 1e-9f; v0 *= v0;
            float v1 = sacc[j][1] * 0.125f + 1e-9f; v1 *= v1;
            float v2 = sacc[j][2] * 0.125f + 1e-9f; v2 *= v2;
            float v3 = sacc[j][3] * 0.125f + 1e-9f; v3 *= v3;
            partial[j] += v0 * g.x + v1 * g.y + v2 * g.z + v3 * g.w;
            uint2 pk = { pack2(v0, v1), pack2(v2, v3) };
            *(uint2*)&As[(wm + j*16 + l15) * 40 + ti*16 + quad*4] = pk;
        }
        __syncthreads();                           // barrier2: As ready
        if (kk < 31) {                             // prefetch next Gbt chunk (in flight across agg)
#pragma unroll
            for (int g4 = 0; g4 < 2; ++g4)
                gl_lds16(Gbt + (size_t)(n0 + br + g4*64) * 1024 + (kk+1)*32 + bc,
                         &Bs[buf^1][(br + g4*64) * 32 + bc]);
        }
        // ---- agg k-step: wave's 64m x 64n
        int kh = quad * 8;
        bf16x8 af[4], bfr[4];
#pragma unroll
        for (int i = 0; i < 4; ++i) af[i] = *(const bf16x8*)&As[(wm + i*16 + l15) * 40 + kh];
#pragma unroll
        for (int j = 0; j < 4; ++j)
            bfr[j] = *(const bf16x8*)&Bs[buf][(wn + j*16 + l15) * 32 + kh];
#pragma unroll
        for (int i = 0; i < 4; ++i)
#pragma unroll
            for (int j = 0; j < 4; ++j)
                acc[i][j] = __builtin_amdgcn_mfma_f32_16x16x32_bf16(af[i], bfr[j], acc[i][j], 0, 0, 0);
    }

    // rowsum: reduce quads (same m, different i-subsets), combine waves via LDS
#pragma unroll
    for (int j = 0; j < 4; ++j) {
        partial[j] += __shfl_xor(partial[j], 16, 64);
        partial[j] += __shfl_xor(partial[j], 32, 64);
    }
    if (quad == 0)
#pragma unroll
        for (int j = 0; j < 4; ++j) atomicAdd(&rs[wm + j*16 + l15], partial[j]);
    __syncthreads();
    if (t < 128) rs[t] = 1.0f / (rs[t] + 0.001f);
    __syncthreads();

#pragma unroll
    for (int i = 0; i < 4; ++i) {
        float4 rv = *(const float4*)&rs[wm + i * 16 + quad * 4];
        float rva[4] = { rv.x, rv.y, rv.z, rv.w };
#pragma unroll
        for (int r = 0; r < 4; ++r) {
            int m = m0 + wm + i * 16 + quad * 4 + r;
            float* orow = out + (size_t)m * (BATCH * IN_DIM) + (size_t)b * IN_DIM + n0 + wn;
#pragma unroll
            for (int j = 0; j < 4; ++j)
                orow[j * 16 + l15] = acc[i][j][r] * rva[r];
        }
    }
}

// ---------------------------------------------------------------------------
extern "C" void kernel_launch(void* const* d_in, const int* in_sizes, int n_in,
                              void* d_out, int out_size, void* d_ws, size_t ws_size,
                              hipStream_t stream) {
    const float* s  = (const float*)d_in[0];
    const float* G  = (const float*)d_in[1];
    const float* Q  = (const float*)d_in[2];
    const float* Kw = (const float*)d_in[3];
    float* out = (float*)d_out;
    char* ws = (char*)d_ws;

    u16*   qws   = (u16*)(ws);                                    // 2 MB
    u16*   ktws  = (u16*)(ws + (size_t)(2u << 20));               // 2 MB
    u16*   Gbt   = (u16*)(ws + (size_t)(4u << 20));               // 2 MB
    u16*   QT    = (u16*)(ws + (size_t)(6u << 20));               // 128 KB
    u16*   KwT   = (u16*)(ws + (size_t)(6u << 20) + (128u << 10)); // 128 KB
    float* Grsum = (float*)(ws + (size_t)(6u << 20) + (256u << 10)); // 4 KB
    float* Grp   = (float*)(ws + (size_t)(6u << 20) + (260u << 10)); // 64 KB

    prep<<<768, 256, 0, stream>>>(G, Q, Kw, Gbt, Grp, QT, KwT);
    qkt<<<dim3(16, 16, 2), 512, 0, stream>>>(s, QT, KwT, Grp, qws, ktws, Grsum);
    gemm_fused<<<dim3(8, 8, 16), 256, 0, stream>>>(qws, ktws, Gbt, Grsum, out);
}

// Round 7
// 211.835 us; speedup vs baseline: 1.3029x; 1.3029x over previous
//
#include <hip/hip_runtime.h>
#include <hip/hip_bf16.h>
#include <stdint.h>

typedef unsigned short u16;
typedef unsigned int   u32;

#define N_DIM  1024
#define IN_DIM 1024
#define H_DIM  64
#define BATCH  16

typedef __bf16 bf16x8 __attribute__((ext_vector_type(8)));
typedef float  f32x4  __attribute__((ext_vector_type(4)));

// round-to-nearest-even fp32 -> bf16 (bit pattern)
__device__ inline u16 f2bf(float f) {
    union { float f; u32 u; } v; v.f = f;
    u32 u = v.u;
    return (u16)((u + 0x7fffu + ((u >> 16) & 1u)) >> 16);
}
// packed pair: v_cvt_pk_bf16_f32 when available
__device__ inline u32 pack2(float a, float b) {
    __hip_bfloat162 h = __float22bfloat162_rn(float2{a, b});
    union { __hip_bfloat162 h; u32 u; } cv; cv.h = h; return cv.u;
}

// async global->LDS, 16B per lane. LDS dest must be wave-uniform base + lane*16.
__device__ inline void gl_lds16(const u16* g, u16* l) {
    __builtin_amdgcn_global_load_lds(
        (const __attribute__((address_space(1))) u32*)g,
        (__attribute__((address_space(3))) u32*)l, 16, 0, 0);
}

// ---------------------------------------------------------------------------
// prep (merged): blocks 0..255 = G transpose tiles + per-jtile rowsum partials
//                blocks 256..767 = Q/Kw transpose-cast
__global__ __launch_bounds__(256) void prep(
        const float* __restrict__ G, const float* __restrict__ Q,
        const float* __restrict__ Kw, u16* __restrict__ Gbt,
        float* __restrict__ Grp, u16* __restrict__ QT, u16* __restrict__ KwT) {
    int bid = blockIdx.x;
    if (bid >= 256) {
        int idx = (bid - 256) * 256 + threadIdx.x;      // 0 .. 131071
        const float* src = (idx < 65536) ? Q : Kw;
        u16* dst = (idx < 65536) ? QT : KwT;
        int i = idx & 65535;
        int h = i >> 10;         // 0..63
        int n = i & 1023;        // 0..1023 (contiguous store)
        dst[h * 1024 + n] = f2bf(src[n * 64 + h]);
        return;
    }
    __shared__ float tile[64][65];
    int jt = bid & 15, it = bid >> 4;
    int i0 = it * 64, j0 = jt * 64;
    int tx = threadIdx.x & 63, ty = threadIdx.x >> 6;   // ty 0..3
    for (int r = 0; r < 16; ++r) {
        int i = ty * 16 + r;
        tile[i][tx] = G[(size_t)(i0 + i) * 1024 + j0 + tx];
    }
    __syncthreads();
    for (int r = 0; r < 16; ++r) {
        int j = ty * 16 + r;
        Gbt[(size_t)(j0 + j) * 1024 + i0 + tx] = f2bf(tile[tx][j]);
    }
    if (ty == 0) {
        float sum = 0.f;
        for (int j = 0; j < 64; ++j) sum += tile[tx][j];
        Grp[jt * 1024 + i0 + tx] = sum;                 // plain store, no atomics
    }
}

// ---------------------------------------------------------------------------
// qkt (merged): z==0 -> q[b][n][h] = sum_i s[n][b][i] Qw[i][h]
//               z==1 -> kt[b][i][h] = sum_n s[n][b][i] Kw[n][h]
__global__ __launch_bounds__(512, 4) void qkt(
        const float* __restrict__ s, const u16* __restrict__ QT,
        const u16* __restrict__ KwT, const float* __restrict__ Grp,
        u16* __restrict__ qws, u16* __restrict__ ktws, float* __restrict__ Grsum) {
    int b = blockIdx.y;
    int t = threadIdx.x, lane = t & 63, w = t >> 6, quad = lane >> 4, l15 = lane & 15;
    __shared__ __align__(16) u16 sh[2][2][64][34];     // kt staging; q aliases as 16KB reduce
    float* red = (float*)sh;

    if (blockIdx.z == 0) {
        // ---------------- q role ----------------
        if (blockIdx.y == 0 && t < 64) {               // Grsum finalize (16 x-blocks cover 1024 i)
            int i = blockIdx.x * 64 + t;
            float g = 0.f;
            for (int jt = 0; jt < 16; ++jt) g += Grp[jt * 1024 + i];
            Grsum[i] = g;
        }
        int n0 = blockIdx.x * 64;
        int wm = (w & 3) * 16;                         // m-quarter within 64
        int kb = (w >> 2) * 512;                       // k-half
        const float* arow = s + (size_t)(n0 + wm + l15) * (BATCH * IN_DIM)
                              + (size_t)b * IN_DIM + kb + quad * 8;
        const u16* bbase = QT + (size_t)l15 * 1024 + kb + quad * 8;

        f32x4 acc[4] = {};
        float4 A0[3], A1[3];
        bf16x8 Bf[2][4];
        A0[0] = ((const float4*)arow)[0];
        A1[0] = ((const float4*)arow)[1];
        A0[1] = ((const float4*)(arow + 32))[0];
        A1[1] = ((const float4*)(arow + 32))[1];
#pragma unroll
        for (int ct = 0; ct < 4; ++ct)
            Bf[0][ct] = *(const bf16x8*)&bbase[ct * 16384];

#pragma unroll
        for (int st = 0; st < 16; ++st) {              // 16 steps of k=32
            int cur = st % 3, cb = st & 1;
            if (st < 14) {                             // A prefetch depth 3 (HBM)
                const float4* ap = (const float4*)(arow + (size_t)(st + 2) * 32);
                A0[(st + 2) % 3] = ap[0];
                A1[(st + 2) % 3] = ap[1];
            }
            if (st < 15) {                             // B prefetch depth 2 (L2)
#pragma unroll
                for (int ct = 0; ct < 4; ++ct)
                    Bf[cb ^ 1][ct] = *(const bf16x8*)&bbase[ct * 16384 + (st + 1) * 32];
            }
            float4 fa = A0[cur], fb = A1[cur];
            union { uint4 u; bf16x8 v; } cu;
            cu.u = (uint4){ pack2(fa.x, fa.y), pack2(fa.z, fa.w),
                            pack2(fb.x, fb.y), pack2(fb.z, fb.w) };
#pragma unroll
            for (int ct = 0; ct < 4; ++ct)
                acc[ct] = __builtin_amdgcn_mfma_f32_16x16x32_bf16(cu.v, Bf[cb][ct], acc[ct], 0, 0, 0);
        }

        // cross-k-half reduce through LDS
        if (w >= 4) {
            float* dst = red + ((w - 4) * 64 + lane) * 16;
#pragma unroll
            for (int ct = 0; ct < 4; ++ct) *(f32x4*)&dst[ct * 4] = acc[ct];
        }
        __syncthreads();
        if (w < 4) {
            const float* sp2 = red + (w * 64 + lane) * 16;
            u16* ob = qws + (size_t)b * 65536;
#pragma unroll
            for (int ct = 0; ct < 4; ++ct) {
                f32x4 o = *(const f32x4*)&sp2[ct * 4];
#pragma unroll
                for (int r = 0; r < 4; ++r) {
                    int m = n0 + wm + quad * 4 + r;
                    ob[(size_t)m * 64 + ct * 16 + l15] = f2bf(acc[ct][r] + o[r]);
                }
            }
        }
        return;
    }

    // ---------------- kt role ----------------
    int i0 = blockIdx.x * 64;
    int half = w >> 2;                                 // compute n-half
    int wm = (w & 3) * 16;                             // i-quarter
    int shalf = t >> 8, nr = (t & 255) >> 3, iofs = (t & 7) * 8;  // staging role
    const float* sp = s + (size_t)(shalf * 512 + nr) * (BATCH * IN_DIM)
                        + (size_t)b * IN_DIM + i0 + iofs;
    const u16* bbase = KwT + (size_t)l15 * 1024 + half * 512 + quad * 8;

    f32x4 acc[4] = {};
    float4 P0[2], P1[2];
    bf16x8 Bf[2][4];
    P0[0] = ((const float4*)sp)[0];
    P1[0] = ((const float4*)sp)[1];
    {
        const float4* p = (const float4*)(sp + (size_t)32 * 16384);
        P0[1] = p[0]; P1[1] = p[1];
    }
#pragma unroll
    for (int ct = 0; ct < 4; ++ct)
        Bf[0][ct] = *(const bf16x8*)&bbase[ct * 16384];

#pragma unroll
    for (int c = 0; c < 16; ++c) {                     // 16 chunks of n=32 per half
        int buf = c & 1;
        float4 fa = P0[buf], fb = P1[buf];
        u16* wp = &sh[shalf][buf][iofs][nr];
        wp[0]   = f2bf(fa.x);
        wp[34]  = f2bf(fa.y);
        wp[68]  = f2bf(fa.z);
        wp[102] = f2bf(fa.w);
        wp[136] = f2bf(fb.x);
        wp[170] = f2bf(fb.y);
        wp[204] = f2bf(fb.z);
        wp[238] = f2bf(fb.w);
        __syncthreads();                               // buf ready (both halves)
        if (c < 14) {                                  // prefetch chunk c+2 (HBM/L3)
            const float4* p = (const float4*)(sp + (size_t)(c + 2) * 32 * 16384);
            P0[buf] = p[0]; P1[buf] = p[1];
        }
        if (c < 15) {                                  // prefetch next B-frags (L2)
#pragma unroll
            for (int ct = 0; ct < 4; ++ct)
                Bf[(c + 1) & 1][ct] = *(const bf16x8*)&bbase[ct * 16384 + (c + 1) * 32];
        }
        const u32* ap = (const u32*)&sh[half][buf][wm + l15][quad * 8];
        union { u32 u[4]; bf16x8 v; } au;
        au.u[0] = ap[0]; au.u[1] = ap[1]; au.u[2] = ap[2]; au.u[3] = ap[3];
#pragma unroll
        for (int ct = 0; ct < 4; ++ct)
            acc[ct] = __builtin_amdgcn_mfma_f32_16x16x32_bf16(au.v, Bf[buf][ct], acc[ct], 0, 0, 0);
    }

    __syncthreads();                                   // staging reads all done
    if (w >= 4) {
        float* dst = red + ((w - 4) * 64 + lane) * 16;
#pragma unroll
        for (int ct = 0; ct < 4; ++ct) *(f32x4*)&dst[ct * 4] = acc[ct];
    }
    __syncthreads();
    if (w < 4) {
        const float* sp2 = red + (w * 64 + lane) * 16;
        u16* ob = ktws + (size_t)b * 65536;
#pragma unroll
        for (int ct = 0; ct < 4; ++ct) {
            f32x4 o = *(const f32x4*)&sp2[ct * 4];
#pragma unroll
            for (int r = 0; r < 4; ++r) {
                int i = i0 + wm + quad * 4 + r;
                ob[(size_t)i * 64 + ct * 16 + l15] = f2bf(acc[ct][r] + o[r]);
            }
        }
    }
}

// ---------------------------------------------------------------------------
// gemm_fused v7: producer/consumer wave specialization on the r2 tile.
// Block = 512 thr (8 waves), grid (4,8,16) = 512 blocks, 1 block/CU.
// Waves 0-3 (producers) = r2's exact score roles: ktc staging, score MFMA,
// square/rowsum/pack epilogue, As write. Waves 4-7 (consumers) = r2's exact
// agg roles: Bs gl_lds staging, As x Bs MFMA into acc[4][8], out epilogue.
// Pipeline: producers fill As[kk&1] at iter kk; consumers drain As[(kk-1)&1]
// at iter kk. One barrier per iter; hazard audit (each crosses 1 barrier):
//   As[sb]  : W@kk by prod, R@kk+1 by cons (RAW ok); re-W@kk+2 (WAR ok)
//   ktc[x]  : W@kk (late) by prod, R@kk+1 by prods (RAW); last R@kk-1 (WAR)
//   Bs[c&3] : gl_lds issue@kk (chunk kk+2), per-wave vmcnt drains at barrier
//             end-of-kk; R@kk+3; last R of that buf @kk-1 (WAR ok)
// Producer VALU epilogue + kreg/ktc stalls now overlap consumer MFMAs on the
// same SIMD (1 producer + 1 consumer per SIMD) instead of serializing.
__global__ __launch_bounds__(512, 2) void gemm_fused(
        const u16* __restrict__ qws, const u16* __restrict__ ktws,
        const u16* __restrict__ Gbt, const float* __restrict__ Grsum,
        float* __restrict__ out) {
    int b = blockIdx.z;
    int n0 = blockIdx.x * 256, m0 = blockIdx.y * 128;
    const u16* qb = qws  + (size_t)b * 65536;
    const u16* kb = ktws + (size_t)b * 65536;
    __shared__ __align__(16) u16 As[2][128 * 40];    // 20480 B, score->agg dbuf
    __shared__ __align__(16) u16 Bs[4][256 * 32];    // 65536 B, Gbt staging 4-deep
    __shared__ __align__(16) u16 ktc[2][32 * 72];    // 9216 B, kt chunk dbuf
    __shared__ __align__(16) float Grs[1024];        // 4096 B
    __shared__ float rs[128];                        // 512 B   (total 99840 B)
    int t = threadIdx.x, lane = t & 63, w = t >> 6, quad = lane >> 4, l15 = lane & 15;

    if (w < 4) {
        // ====================== producers: score ======================
        int ti = w & 1;                          // i-subtile (16 of 32)
        int wm = (w >> 1) * 64;                  // m-half of 128
        ((float4*)Grs)[t] = ((const float4*)Grsum)[t];   // t<256 covers 1024 f32
        if (t < 128) rs[t] = 0.f;

        bf16x8 qf[4][2];                         // K-invariant q B-frags
#pragma unroll
        for (int j = 0; j < 4; ++j)
#pragma unroll
            for (int kick = 0; kick < 2; ++kick)
                qf[j][kick] = *(const bf16x8*)&qb[(size_t)(m0 + wm + j*16 + l15) * 64 + kick*32 + quad*8];

        int ir = t >> 3, ch = (t & 7) * 8;       // ktc staging role (256 thr)
        {
            uint4 k0 = *(const uint4*)&kb[(size_t)ir * 64 + ch];
            *(uint4*)&ktc[0][ir * 72 + ch] = k0;
        }
        float partial[4] = {0.f, 0.f, 0.f, 0.f};
        __syncthreads();                         // P0: ktc[0], Bs[0..1] ready

        for (int kk = 0; kk <= 32; ++kk) {
            if (kk < 32) {
                int sb = kk & 1;
                // score step kk: S^T[i][m], i-subtile ti, m in wave's 64-half
                f32x4 sacc[4] = {};
#pragma unroll
                for (int kick = 0; kick < 2; ++kick) {
                    bf16x8 ktf = *(const bf16x8*)&ktc[sb][(ti*16 + l15) * 72 + kick*32 + quad*8];
#pragma unroll
                    for (int j = 0; j < 4; ++j)
                        sacc[j] = __builtin_amdgcn_mfma_f32_16x16x32_bf16(ktf, qf[j][kick], sacc[j], 0, 0, 0);
                }
                uint4 kregn;
                if (kk < 31)                     // next kt chunk (L2); used ~400cy later
                    kregn = *(const uint4*)&kb[(size_t)((kk + 1) * 32 + ir) * 64 + ch];
                // epilogue: square, weighted rowsum partial, pack to As[sb]
                float4 g = *(const float4*)&Grs[kk * 32 + ti * 16 + quad * 4];
#pragma unroll
                for (int j = 0; j < 4; ++j) {
                    float v0 = sacc[j][0] * 0.125f + 1e-9f; v0 *= v0;
                    float v1 = sacc[j][1] * 0.125f + 1e-9f; v1 *= v1;
                    float v2 = sacc[j][2] * 0.125f + 1e-9f; v2 *= v2;
                    float v3 = sacc[j][3] * 0.125f + 1e-9f; v3 *= v3;
                    partial[j] += v0 * g.x + v1 * g.y + v2 * g.z + v3 * g.w;
                    uint2 pk = { pack2(v0, v1), pack2(v2, v3) };
                    *(uint2*)&As[sb][(wm + j*16 + l15) * 40 + ti*16 + quad*4] = pk;
                }
                if (kk < 31)                     // stage chunk kk+1 (readers were @kk-1)
                    *(uint4*)&ktc[sb ^ 1][ir * 72 + ch] = kregn;
            }
            __syncthreads();                     // barrier #kk+1
        }

        // rowsum: reduce quads (same m, different i-subsets), merge ti-waves
#pragma unroll
        for (int j = 0; j < 4; ++j) {
            partial[j] += __shfl_xor(partial[j], 16, 64);
            partial[j] += __shfl_xor(partial[j], 32, 64);
        }
        if (quad == 0)
#pragma unroll
            for (int j = 0; j < 4; ++j) atomicAdd(&rs[wm + j*16 + l15], partial[j]);
        __syncthreads();                         // T1
        if (t < 128) rs[t] = 1.0f / (rs[t] + 0.001f);
        __syncthreads();                         // T2
    } else {
        // ====================== consumers: agg ======================
        int wc = w - 4;
        int wm = (wc >> 1) * 64;                 // m-half (rows of As)
        int wn = (wc & 1) * 128;                 // n-half of 256
        int ts = t & 255, br = ts >> 2, bc = (ts & 3) * 8;   // Bs staging role
        // prologue: stage Gbt chunks 0,1 -> Bs[0],Bs[1]
#pragma unroll
        for (int c0 = 0; c0 < 2; ++c0)
#pragma unroll
            for (int g4 = 0; g4 < 4; ++g4)
                gl_lds16(Gbt + (size_t)(n0 + br + g4*64) * 1024 + c0*32 + bc,
                         &Bs[c0][(br + g4*64) * 32 + bc]);
        f32x4 acc[4][8] = {};
        __syncthreads();                         // P0 (drains our gl_lds)

        for (int kk = 0; kk <= 32; ++kk) {
            if (kk > 0) {
                // agg step kk-1: wave's 64m x 128n from As[(kk-1)&1] @ Bs[(kk-1)&3]
                int ab = (kk - 1) & 1, bb = (kk - 1) & 3;
                int kh = quad * 8;
                bf16x8 af[4];
#pragma unroll
                for (int i = 0; i < 4; ++i)
                    af[i] = *(const bf16x8*)&As[ab][(wm + i*16 + l15) * 40 + kh];
#pragma unroll
                for (int jh = 0; jh < 2; ++jh) {
                    bf16x8 bfr[4];
#pragma unroll
                    for (int j = 0; j < 4; ++j)
                        bfr[j] = *(const bf16x8*)&Bs[bb][(wn + jh*64 + j*16 + l15) * 32 + kh];
#pragma unroll
                    for (int i = 0; i < 4; ++i)
#pragma unroll
                        for (int j = 0; j < 4; ++j)
                            acc[i][jh*4 + j] = __builtin_amdgcn_mfma_f32_16x16x32_bf16(af[i], bfr[j], acc[i][jh*4 + j], 0, 0, 0);
                }
            }
            if (kk < 30) {                       // stage chunk kk+2 -> Bs[(kk+2)&3]
                int dst = (kk + 2) & 3;
#pragma unroll
                for (int g4 = 0; g4 < 4; ++g4)
                    gl_lds16(Gbt + (size_t)(n0 + br + g4*64) * 1024 + (kk+2)*32 + bc,
                             &Bs[dst][(br + g4*64) * 32 + bc]);
            }
            __syncthreads();                     // barrier #kk+1
        }

        __syncthreads();                         // T1 (match producers' atomic barrier)
        __syncthreads();                         // T2 (rs finalized)

        // out epilogue: scale by 1/(rowsum+1e-3), write (n,B,j) fp32
#pragma unroll
        for (int i = 0; i < 4; ++i) {
            float4 rv = *(const float4*)&rs[wm + i * 16 + quad * 4];
            float rva[4] = { rv.x, rv.y, rv.z, rv.w };
#pragma unroll
            for (int r = 0; r < 4; ++r) {
                int m = m0 + wm + i * 16 + quad * 4 + r;
                float* orow = out + (size_t)m * (BATCH * IN_DIM) + (size_t)b * IN_DIM + n0 + wn;
#pragma unroll
                for (int j = 0; j < 8; ++j)
                    orow[j * 16 + l15] = acc[i][j][r] * rva[r];
            }
        }
    }
}

// ---------------------------------------------------------------------------
extern "C" void kernel_launch(void* const* d_in, const int* in_sizes, int n_in,
                              void* d_out, int out_size, void* d_ws, size_t ws_size,
                              hipStream_t stream) {
    const float* s  = (const float*)d_in[0];
    const float* G  = (const float*)d_in[1];
    const float* Q  = (const float*)d_in[2];
    const float* Kw = (const float*)d_in[3];
    float* out = (float*)d_out;
    char* ws = (char*)d_ws;

    u16*   qws   = (u16*)(ws);                                    // 2 MB
    u16*   ktws  = (u16*)(ws + (size_t)(2u << 20));               // 2 MB
    u16*   Gbt   = (u16*)(ws + (size_t)(4u << 20));               // 2 MB
    u16*   QT    = (u16*)(ws + (size_t)(6u << 20));               // 128 KB
    u16*   KwT   = (u16*)(ws + (size_t)(6u << 20) + (128u << 10)); // 128 KB
    float* Grsum = (float*)(ws + (size_t)(6u << 20) + (256u << 10)); // 4 KB
    float* Grp   = (float*)(ws + (size_t)(6u << 20) + (260u << 10)); // 64 KB

    prep<<<768, 256, 0, stream>>>(G, Q, Kw, Gbt, Grp, QT, KwT);
    qkt<<<dim3(16, 16, 2), 512, 0, stream>>>(s, QT, KwT, Grp, qws, ktws, Grsum);
    gemm_fused<<<dim3(4, 8, 16), 512, 0, stream>>>(qws, ktws, Gbt, Grsum, out);
}

// Round 8
// 198.279 us; speedup vs baseline: 1.3920x; 1.0684x over previous
//
#include <hip/hip_runtime.h>
#include <hip/hip_bf16.h>
#include <stdint.h>

typedef unsigned short u16;
typedef unsigned int   u32;

#define N_DIM  1024
#define IN_DIM 1024
#define H_DIM  64
#define BATCH  16

typedef __bf16 bf16x8 __attribute__((ext_vector_type(8)));
typedef float  f32x4  __attribute__((ext_vector_type(4)));

// round-to-nearest-even fp32 -> bf16 (bit pattern)
__device__ inline u16 f2bf(float f) {
    union { float f; u32 u; } v; v.f = f;
    u32 u = v.u;
    return (u16)((u + 0x7fffu + ((u >> 16) & 1u)) >> 16);
}
// packed pair: v_cvt_pk_bf16_f32 when available
__device__ inline u32 pack2(float a, float b) {
    __hip_bfloat162 h = __float22bfloat162_rn(float2{a, b});
    union { __hip_bfloat162 h; u32 u; } cv; cv.h = h; return cv.u;
}

// async global->LDS, 16B per lane. LDS dest must be wave-uniform base + lane*16.
__device__ inline void gl_lds16(const u16* g, u16* l) {
    __builtin_amdgcn_global_load_lds(
        (const __attribute__((address_space(1))) u32*)g,
        (__attribute__((address_space(3))) u32*)l, 16, 0, 0);
}

// ---------------------------------------------------------------------------
// prep (merged): blocks 0..255 = G transpose tiles + per-jtile rowsum partials
//                blocks 256..767 = Q/Kw transpose-cast
__global__ __launch_bounds__(256) void prep(
        const float* __restrict__ G, const float* __restrict__ Q,
        const float* __restrict__ Kw, u16* __restrict__ Gbt,
        float* __restrict__ Grp, u16* __restrict__ QT, u16* __restrict__ KwT) {
    int bid = blockIdx.x;
    if (bid >= 256) {
        int idx = (bid - 256) * 256 + threadIdx.x;      // 0 .. 131071
        const float* src = (idx < 65536) ? Q : Kw;
        u16* dst = (idx < 65536) ? QT : KwT;
        int i = idx & 65535;
        int h = i >> 10;         // 0..63
        int n = i & 1023;        // 0..1023 (contiguous store)
        dst[h * 1024 + n] = f2bf(src[n * 64 + h]);
        return;
    }
    __shared__ float tile[64][65];
    int jt = bid & 15, it = bid >> 4;
    int i0 = it * 64, j0 = jt * 64;
    int tx = threadIdx.x & 63, ty = threadIdx.x >> 6;   // ty 0..3
    for (int r = 0; r < 16; ++r) {
        int i = ty * 16 + r;
        tile[i][tx] = G[(size_t)(i0 + i) * 1024 + j0 + tx];
    }
    __syncthreads();
    for (int r = 0; r < 16; ++r) {
        int j = ty * 16 + r;
        Gbt[(size_t)(j0 + j) * 1024 + i0 + tx] = f2bf(tile[tx][j]);
    }
    if (ty == 0) {
        float sum = 0.f;
        for (int j = 0; j < 64; ++j) sum += tile[tx][j];
        Grp[jt * 1024 + i0 + tx] = sum;                 // plain store, no atomics
    }
}

// ---------------------------------------------------------------------------
// qkt (merged): z==0 -> q[b][n][h] = sum_i s[n][b][i] Qw[i][h]
//               z==1 -> kt[b][i][h] = sum_n s[n][b][i] Kw[n][h]
__global__ __launch_bounds__(512, 4) void qkt(
        const float* __restrict__ s, const u16* __restrict__ QT,
        const u16* __restrict__ KwT, const float* __restrict__ Grp,
        u16* __restrict__ qws, u16* __restrict__ ktws, float* __restrict__ Grsum) {
    int b = blockIdx.y;
    int t = threadIdx.x, lane = t & 63, w = t >> 6, quad = lane >> 4, l15 = lane & 15;
    __shared__ __align__(16) u16 sh[2][2][64][34];     // kt staging; q aliases as 16KB reduce
    float* red = (float*)sh;

    if (blockIdx.z == 0) {
        // ---------------- q role ----------------
        if (blockIdx.y == 0 && t < 64) {               // Grsum finalize (16 x-blocks cover 1024 i)
            int i = blockIdx.x * 64 + t;
            float g = 0.f;
            for (int jt = 0; jt < 16; ++jt) g += Grp[jt * 1024 + i];
            Grsum[i] = g;
        }
        int n0 = blockIdx.x * 64;
        int wm = (w & 3) * 16;                         // m-quarter within 64
        int kb = (w >> 2) * 512;                       // k-half
        const float* arow = s + (size_t)(n0 + wm + l15) * (BATCH * IN_DIM)
                              + (size_t)b * IN_DIM + kb + quad * 8;
        const u16* bbase = QT + (size_t)l15 * 1024 + kb + quad * 8;

        f32x4 acc[4] = {};
        float4 A0[3], A1[3];
        bf16x8 Bf[2][4];
        A0[0] = ((const float4*)arow)[0];
        A1[0] = ((const float4*)arow)[1];
        A0[1] = ((const float4*)(arow + 32))[0];
        A1[1] = ((const float4*)(arow + 32))[1];
#pragma unroll
        for (int ct = 0; ct < 4; ++ct)
            Bf[0][ct] = *(const bf16x8*)&bbase[ct * 16384];

#pragma unroll
        for (int st = 0; st < 16; ++st) {              // 16 steps of k=32
            int cur = st % 3, cb = st & 1;
            if (st < 14) {                             // A prefetch depth 3 (HBM)
                const float4* ap = (const float4*)(arow + (size_t)(st + 2) * 32);
                A0[(st + 2) % 3] = ap[0];
                A1[(st + 2) % 3] = ap[1];
            }
            if (st < 15) {                             // B prefetch depth 2 (L2)
#pragma unroll
                for (int ct = 0; ct < 4; ++ct)
                    Bf[cb ^ 1][ct] = *(const bf16x8*)&bbase[ct * 16384 + (st + 1) * 32];
            }
            float4 fa = A0[cur], fb = A1[cur];
            union { uint4 u; bf16x8 v; } cu;
            cu.u = (uint4){ pack2(fa.x, fa.y), pack2(fa.z, fa.w),
                            pack2(fb.x, fb.y), pack2(fb.z, fb.w) };
#pragma unroll
            for (int ct = 0; ct < 4; ++ct)
                acc[ct] = __builtin_amdgcn_mfma_f32_16x16x32_bf16(cu.v, Bf[cb][ct], acc[ct], 0, 0, 0);
        }

        // cross-k-half reduce through LDS
        if (w >= 4) {
            float* dst = red + ((w - 4) * 64 + lane) * 16;
#pragma unroll
            for (int ct = 0; ct < 4; ++ct) *(f32x4*)&dst[ct * 4] = acc[ct];
        }
        __syncthreads();
        if (w < 4) {
            const float* sp2 = red + (w * 64 + lane) * 16;
            u16* ob = qws + (size_t)b * 65536;
#pragma unroll
            for (int ct = 0; ct < 4; ++ct) {
                f32x4 o = *(const f32x4*)&sp2[ct * 4];
#pragma unroll
                for (int r = 0; r < 4; ++r) {
                    int m = n0 + wm + quad * 4 + r;
                    ob[(size_t)m * 64 + ct * 16 + l15] = f2bf(acc[ct][r] + o[r]);
                }
            }
        }
        return;
    }

    // ---------------- kt role ----------------
    int i0 = blockIdx.x * 64;
    int half = w >> 2;                                 // compute n-half
    int wm = (w & 3) * 16;                             // i-quarter
    int shalf = t >> 8, nr = (t & 255) >> 3, iofs = (t & 7) * 8;  // staging role
    const float* sp = s + (size_t)(shalf * 512 + nr) * (BATCH * IN_DIM)
                        + (size_t)b * IN_DIM + i0 + iofs;
    const u16* bbase = KwT + (size_t)l15 * 1024 + half * 512 + quad * 8;

    f32x4 acc[4] = {};
    float4 P0[2], P1[2];
    bf16x8 Bf[2][4];
    P0[0] = ((const float4*)sp)[0];
    P1[0] = ((const float4*)sp)[1];
    {
        const float4* p = (const float4*)(sp + (size_t)32 * 16384);
        P0[1] = p[0]; P1[1] = p[1];
    }
#pragma unroll
    for (int ct = 0; ct < 4; ++ct)
        Bf[0][ct] = *(const bf16x8*)&bbase[ct * 16384];

#pragma unroll
    for (int c = 0; c < 16; ++c) {                     // 16 chunks of n=32 per half
        int buf = c & 1;
        float4 fa = P0[buf], fb = P1[buf];
        u16* wp = &sh[shalf][buf][iofs][nr];
        wp[0]   = f2bf(fa.x);
        wp[34]  = f2bf(fa.y);
        wp[68]  = f2bf(fa.z);
        wp[102] = f2bf(fa.w);
        wp[136] = f2bf(fb.x);
        wp[170] = f2bf(fb.y);
        wp[204] = f2bf(fb.z);
        wp[238] = f2bf(fb.w);
        __syncthreads();                               // buf ready (both halves)
        if (c < 14) {                                  // prefetch chunk c+2 (HBM/L3)
            const float4* p = (const float4*)(sp + (size_t)(c + 2) * 32 * 16384);
            P0[buf] = p[0]; P1[buf] = p[1];
        }
        if (c < 15) {                                  // prefetch next B-frags (L2)
#pragma unroll
            for (int ct = 0; ct < 4; ++ct)
                Bf[(c + 1) & 1][ct] = *(const bf16x8*)&bbase[ct * 16384 + (c + 1) * 32];
        }
        const u32* ap = (const u32*)&sh[half][buf][wm + l15][quad * 8];
        union { u32 u[4]; bf16x8 v; } au;
        au.u[0] = ap[0]; au.u[1] = ap[1]; au.u[2] = ap[2]; au.u[3] = ap[3];
#pragma unroll
        for (int ct = 0; ct < 4; ++ct)
            acc[ct] = __builtin_amdgcn_mfma_f32_16x16x32_bf16(au.v, Bf[buf][ct], acc[ct], 0, 0, 0);
    }

    __syncthreads();                                   // staging reads all done
    if (w >= 4) {
        float* dst = red + ((w - 4) * 64 + lane) * 16;
#pragma unroll
        for (int ct = 0; ct < 4; ++ct) *(f32x4*)&dst[ct * 4] = acc[ct];
    }
    __syncthreads();
    if (w < 4) {
        const float* sp2 = red + (w * 64 + lane) * 16;
        u16* ob = ktws + (size_t)b * 65536;
#pragma unroll
        for (int ct = 0; ct < 4; ++ct) {
            f32x4 o = *(const f32x4*)&sp2[ct * 4];
#pragma unroll
            for (int r = 0; r < 4; ++r) {
                int i = i0 + wm + quad * 4 + r;
                ob[(size_t)i * 64 + ct * 16 + l15] = f2bf(acc[ct][r] + o[r]);
            }
        }
    }
}

// ---------------------------------------------------------------------------
// gemm_fused v8 = r2's proven kernel (61.5us, best of 6 structures) with ONLY
// the barrier waits tightened (T4 counted-vmcnt, minimal form):
//   - Bs deepened 2->3; prefetch issues chunk kk+2 (~1.5 iters in flight)
//   - barrier1: s_waitcnt vmcnt(4) lgkmcnt(0) + raw s_barrier
//       (oldest 4 gl_lds = chunk kk forced complete; chunk kk+2's 4 may fly;
//        lgkmcnt(0) publishes this iter's ktc ds_writes)
//   - barrier2: s_waitcnt lgkmcnt(0) + raw s_barrier
//       (publishes As ds_writes; kreg + gl_lds sail through un-drained)
// Hazard audit (every RAW/WAR crosses >=1 barrier with the right counter):
//   Bs[c%3]: lands by b1(c) [vmcnt(4)]; read agg(c); rewrite (c+3) issued
//            post-b2(c+1) > last read. ktc: W top(kk+1) vs R score(kk):
//            readers drain own lgkm at b2(kk). As: R agg(kk) drained at
//            b1(kk+1) lgkmcnt(0) before W score(kk+1).
// All addresses/roles/layouts byte-identical to r2. LDS 68608 -> 2 blocks/CU.
__global__ __launch_bounds__(256, 2) void gemm_fused(
        const u16* __restrict__ qws, const u16* __restrict__ ktws,
        const u16* __restrict__ Gbt, const float* __restrict__ Grsum,
        float* __restrict__ out) {
    int b = blockIdx.z;
    int n0 = blockIdx.x * 256, m0 = blockIdx.y * 128;
    const u16* qb = qws  + (size_t)b * 65536;
    const u16* kb = ktws + (size_t)b * 65536;
    __shared__ __align__(16) u16 As[128 * 40];       // score->agg buffer, padded
    __shared__ __align__(16) u16 Bs[3][256 * 32];    // Gbt staging (gl_lds, 3-deep)
    __shared__ __align__(16) u16 ktc[32 * 72];       // kt chunk, padded, single buf
    __shared__ __align__(16) float Grs[1024];
    __shared__ float rs[128];
    int t = threadIdx.x, lane = t & 63, w = t >> 6, quad = lane >> 4, l15 = lane & 15;
    int ti = w & 1;                              // score i-subtile (16 of 32)
    int wm = (w >> 1) * 64;                      // m-half (shared by score & agg)
    int wn = (w & 1) * 128;                      // agg n-half of 256

    ((float4*)Grs)[t] = ((const float4*)Grsum)[t];
    if (t < 128) rs[t] = 0.f;

    // K-invariant q B-frags: B[k=h][col=m], 8 contiguous h per lane
    bf16x8 qf[4][2];
    for (int j = 0; j < 4; ++j)
        for (int kick = 0; kick < 2; ++kick)
            qf[j][kick] = *(const bf16x8*)&qb[(size_t)(m0 + wm + j*16 + l15) * 64 + kick*32 + quad*8];

    // prologue staging: Gbt chunks 0 and 1 -> Bs[0], Bs[1]
    int br = t >> 2, bc = (t & 3) * 8;
    for (int c0 = 0; c0 < 2; ++c0)
        for (int g4 = 0; g4 < 4; ++g4)
            gl_lds16(Gbt + (size_t)(n0 + br + g4*64) * 1024 + c0*32 + bc,
                     &Bs[c0][(br + g4*64) * 32 + bc]);
    int ir = t >> 3, ch = (t & 7) * 8;
    uint4 kreg = *(const uint4*)&kb[(size_t)ir * 64 + ch];

    f32x4 acc[4][8] = {};
    float partial[4] = {0.f, 0.f, 0.f, 0.f};

    for (int kk = 0; kk < 32; ++kk) {
        int buf = kk % 3;
        *(uint4*)&ktc[ir * 72 + ch] = kreg;        // single buf: prev reads done pre-barrier2
        // ---- barrier1: chunk kk landed (vmcnt<=4 leaves only chunk kk+1/kk+2
        //      in flight), ktc published. Raw barrier: no full drain.
        asm volatile("s_waitcnt vmcnt(4) lgkmcnt(0)" ::: "memory");
        __builtin_amdgcn_sched_barrier(0);
        __builtin_amdgcn_s_barrier();
        __builtin_amdgcn_sched_barrier(0);
        // ---- score: S^T[i][m] for i-subtile ti, m in wave's 64-half
        f32x4 sacc[4] = {};
        for (int kick = 0; kick < 2; ++kick) {
            bf16x8 ktf = *(const bf16x8*)&ktc[(ti*16 + l15) * 72 + kick*32 + quad*8];
            for (int j = 0; j < 4; ++j)
                sacc[j] = __builtin_amdgcn_mfma_f32_16x16x32_bf16(ktf, qf[j][kick], sacc[j], 0, 0, 0);
        }
        if (kk < 31)
            kreg = *(const uint4*)&kb[(size_t)((kk + 1) * 32 + ir) * 64 + ch];
        // ---- epilogue: square, rowsum partial, pack to As
        float4 g = *(const float4*)&Grs[kk * 32 + ti * 16 + quad * 4];
        for (int j = 0; j < 4; ++j) {
            float v0 = sacc[j][0] * 0.125f + 1e-9f; v0 *= v0;
            float v1 = sacc[j][1] * 0.125f + 1e-9f; v1 *= v1;
            float v2 = sacc[j][2] * 0.125f + 1e-9f; v2 *= v2;
            float v3 = sacc[j][3] * 0.125f + 1e-9f; v3 *= v3;
            partial[j] += v0 * g.x + v1 * g.y + v2 * g.z + v3 * g.w;
            uint2 pk = { pack2(v0, v1), pack2(v2, v3) };
            *(uint2*)&As[(wm + j*16 + l15) * 40 + ti*16 + quad*4] = pk;
        }
        // ---- barrier2: As published; kreg + gl_lds stay in flight (no vmcnt)
        asm volatile("s_waitcnt lgkmcnt(0)" ::: "memory");
        __builtin_amdgcn_sched_barrier(0);
        __builtin_amdgcn_s_barrier();
        __builtin_amdgcn_sched_barrier(0);
        if (kk < 30) {                             // issue chunk kk+2 (consumed at agg kk+2;
            int dst = (kk + 2) % 3;                //  lands by b1(kk+2) via vmcnt(4))
            for (int g4 = 0; g4 < 4; ++g4)
                gl_lds16(Gbt + (size_t)(n0 + br + g4*64) * 1024 + (kk+2)*32 + bc,
                         &Bs[dst][(br + g4*64) * 32 + bc]);
        }
        // ---- agg k-step: wave's 64m x 128n
        int kh = quad * 8;
        bf16x8 af[4];
        for (int i = 0; i < 4; ++i) af[i] = *(const bf16x8*)&As[(wm + i*16 + l15) * 40 + kh];
        for (int jh = 0; jh < 2; ++jh) {
            bf16x8 bfr[4];
            for (int j = 0; j < 4; ++j)
                bfr[j] = *(const bf16x8*)&Bs[buf][(wn + jh*64 + j*16 + l15) * 32 + kh];
            for (int i = 0; i < 4; ++i)
                for (int j = 0; j < 4; ++j)
                    acc[i][jh*4 + j] = __builtin_amdgcn_mfma_f32_16x16x32_bf16(af[i], bfr[j], acc[i][jh*4 + j], 0, 0, 0);
        }
    }

    // rowsum: reduce quads (same m, different i-subsets), combine waves via LDS
    for (int j = 0; j < 4; ++j) {
        partial[j] += __shfl_xor(partial[j], 16, 64);
        partial[j] += __shfl_xor(partial[j], 32, 64);
    }
    if (quad == 0)
        for (int j = 0; j < 4; ++j) atomicAdd(&rs[wm + j*16 + l15], partial[j]);
    __syncthreads();
    if (t < 128) rs[t] = 1.0f / (rs[t] + 0.001f);
    __syncthreads();

    for (int i = 0; i < 4; ++i) {
        float4 rv = *(const float4*)&rs[wm + i * 16 + quad * 4];
        float rva[4] = { rv.x, rv.y, rv.z, rv.w };
        for (int r = 0; r < 4; ++r) {
            int m = m0 + wm + i * 16 + quad * 4 + r;
            float* orow = out + (size_t)m * (BATCH * IN_DIM) + (size_t)b * IN_DIM + n0 + wn;
            for (int j = 0; j < 8; ++j)
                orow[j * 16 + l15] = acc[i][j][r] * rva[r];
        }
    }
}

// ---------------------------------------------------------------------------
extern "C" void kernel_launch(void* const* d_in, const int* in_sizes, int n_in,
                              void* d_out, int out_size, void* d_ws, size_t ws_size,
                              hipStream_t stream) {
    const float* s  = (const float*)d_in[0];
    const float* G  = (const float*)d_in[1];
    const float* Q  = (const float*)d_in[2];
    const float* Kw = (const float*)d_in[3];
    float* out = (float*)d_out;
    char* ws = (char*)d_ws;

    u16*   qws   = (u16*)(ws);                                    // 2 MB
    u16*   ktws  = (u16*)(ws + (size_t)(2u << 20));               // 2 MB
    u16*   Gbt   = (u16*)(ws + (size_t)(4u << 20));               // 2 MB
    u16*   QT    = (u16*)(ws + (size_t)(6u << 20));               // 128 KB
    u16*   KwT   = (u16*)(ws + (size_t)(6u << 20) + (128u << 10)); // 128 KB
    float* Grsum = (float*)(ws + (size_t)(6u << 20) + (256u << 10)); // 4 KB
    float* Grp   = (float*)(ws + (size_t)(6u << 20) + (260u << 10)); // 64 KB

    prep<<<768, 256, 0, stream>>>(G, Q, Kw, Gbt, Grp, QT, KwT);
    qkt<<<dim3(16, 16, 2), 512, 0, stream>>>(s, QT, KwT, Grp, qws, ktws, Grsum);
    gemm_fused<<<dim3(4, 8, 16), 256, 0, stream>>>(qws, ktws, Gbt, Grsum, out);
}